// Round 20
// baseline (166.902 us; speedup 1.0000x reference)
//
#include <hip/hip_runtime.h>
#include <math.h>

#define Bn 16
#define Cn 64
#define Hn 192
#define Wn 192
#define NPIX (Bn * Cn * Hn * Wn)   // 37748736
#define NBLKS 512
#define WCOLS 98
#define SLOTB (WCOLS * 128)        // 12544 B per window row-slot

typedef short bf16x8 __attribute__((ext_vector_type(8)));
typedef float f32x4 __attribute__((ext_vector_type(4)));
typedef __attribute__((address_space(1))) const unsigned int as1_u32;
typedef __attribute__((address_space(3))) unsigned int as3_u32;

// g_Ms[9 slices][64 rows][64 c] bf16; within a row, c-octet g stored at slot (g ^ (p&7)).
__device__ __align__(16) unsigned short g_Ms[9 * 64 * 64];
__device__ __align__(16) float g_b2[64];

static __device__ __forceinline__ unsigned short f2bf(float f) {
    union { float f; unsigned u; } x; x.f = f;
    unsigned r = x.u + 0x7fffu + ((x.u >> 16) & 1u);   // RNE
    return (unsigned short)(r >> 16);
}

__global__ void acdc_precompute(const float* __restrict__ cw, const float* __restrict__ A,
                                const float* __restrict__ D, const float* __restrict__ bias,
                                const int* __restrict__ perm) {
    __shared__ float mre[64];
    int p = blockIdx.x;
    int t = threadIdx.x;
    if (t < 64) {
        float re = 0.f;
        for (int k = 0; k < 64; ++k) {
            int a = (k * t) & 63;
            re += D[k] * cosf((float)a * 0.0981747704246810387f);  // pi/32
        }
        mre[t] = re;
    }
    __syncthreads();
    int pp = perm[p];
    for (int k0 = t; k0 < 576; k0 += 256) {
        int sp = k0 >> 6, c = k0 & 63;
        int g = c >> 3, cil = c & 7;
        float val = 0.f;
        for (int o = 0; o < 8; ++o) {
            int oc = g * 8 + o;
            float gco = mre[(pp - oc + 64) & 63] * A[oc] * (0.125f / 64.0f);
            val += gco * cw[(oc * 8 + cil) * 9 + sp];
        }
        g_Ms[((sp * 64 + p) << 6) + (((g ^ (p & 7)) << 3) | cil)] = f2bf(val);
    }
    if (p == 0 && t < 64)
        g_b2[t] = bias[perm[t]] * 0.125f;
}

// Persistent-ish: 512 blocks x 1024 thr (1/CU, 2 rounds). Block = image x 12-row band
// x HALF width (96+2 cols). 4-row steps; 6-slot circular window. Wave = 2m x 3n tile
// (5 LDS reads per 6 MFMAs vs R19's 4/3) -> per-row reads 1152 -> 720. M in LDS once.
__global__ __launch_bounds__(1024)
void acdc_main(const float* __restrict__ x, float* __restrict__ out) {
    __shared__ __align__(16) unsigned short Mlds[9 * 64 * 64];   // 73728 B
    __shared__ __align__(16) unsigned char xsb[6 * SLOTB];       // 75264 B

    int tid = threadIdx.x;
    int lane = tid & 63, wv = tid >> 6;
    // bijective XCD swizzle (512 % 8 == 0): XCD k gets 64 consecutive logical blocks
    int Lb = (blockIdx.x & 7) * (NBLKS / 8) + (blockIdx.x >> 3);
    int bb = Lb >> 5;                 // image
    int band = (Lb >> 1) & 15;        // 12-row band
    int half = Lb & 1;                // width half
    int h0 = band * 12;
    int cbase = half * 96;

    // ---- stage M once: 72 x 1KB chunks via global_load_lds ----
    #pragma unroll
    for (int k = 0; k < 5; ++k) {
        int chunk = wv + k * 16;
        if (chunk < 72) {
            const unsigned char* src = (const unsigned char*)g_Ms + chunk * 1024 + lane * 16;
            __builtin_amdgcn_global_load_lds((as1_u32*)(const void*)src,
                (as3_u32*)(void*)((unsigned char*)Mlds + chunk * 1024), 16, 0, 0);
        }
    }

    int pxw = lane & 15, q = lane >> 4, rlane = lane & 15;
    int r = wv & 3;                   // row within 4-row step
    int mg = (wv >> 2) & 1;           // m-pair: m-tiles {2mg, 2mg+1}
    int ngg = wv >> 3;                // n-group: 3 n-tiles at cols ngg*48..+47

    const float* xb = x + (size_t)bb * Cn * Hn * Wn;

    // ---- prologue: stage rows h0-1 .. h0+4 -> slots 0..5 (fused load+write) ----
    for (int k = 0; k < 5; ++k) {
        int idx = tid + (k << 10);
        if (idx >= 4992) break;
        int f = idx % 26;
        int rr = (idx / 26) % 6;
        int cp = idx / 156;
        int gi = h0 - 1 + rr;
        int gc0 = cbase - 4 + 4 * f;
        float av[4] = {0.f, 0.f, 0.f, 0.f}, bv[4] = {0.f, 0.f, 0.f, 0.f};
        bool giok = (unsigned)gi < (unsigned)Hn;
        const float* r0 = xb + ((size_t)(2 * cp) * Hn + (giok ? gi : 0)) * Wn;
        const float* r1 = r0 + Hn * Wn;
        if (giok) {
            if (gc0 >= 0 && gc0 <= Wn - 4) {
                float4 a = *(const float4*)(r0 + gc0);
                float4 b = *(const float4*)(r1 + gc0);
                av[0]=a.x; av[1]=a.y; av[2]=a.z; av[3]=a.w;
                bv[0]=b.x; bv[1]=b.y; bv[2]=b.z; bv[3]=b.w;
            } else {
                #pragma unroll
                for (int j = 0; j < 4; ++j) {
                    int gc = gc0 + j;
                    if ((unsigned)gc < (unsigned)Wn) { av[j] = r0[gc]; bv[j] = r1[gc]; }
                }
            }
        }
        int slot = rr;                       // (gi+1)%6 == rr since h0%6==0
        int chunk = cp >> 2, sub = (cp & 3) * 4;
        #pragma unroll
        for (int j = 0; j < 4; ++j) {
            int c2 = 4 * f + j - 3;
            if ((unsigned)c2 >= (unsigned)WCOLS) continue;
            unsigned u;
            asm("v_cvt_pk_bf16_f32 %0, %1, %2" : "=v"(u) : "v"(av[j]), "v"(bv[j]));
            int key = (c2 + (c2 >> 3) + 3 * slot) & 7;
            *(unsigned*)(xsb + slot * SLOTB + c2 * 128 + ((chunk ^ key) << 4) + sub) = u;
        }
    }
    __syncthreads();   // publishes M + initial 6-row window

    float4 va[4], vb[4];
    for (int t = 0; t < 3; ++t) {
        int hb = h0 + 4 * t;
        int S = (t == 0) ? 0 : (t == 1) ? 4 : 2;      // hb % 6

        // ---- xload: rows hb+5..hb+8 to regs (retires under compute) ----
        if (t < 2) {
            #pragma unroll
            for (int k = 0; k < 4; ++k) {
                int idx = tid + (k << 10);
                va[k] = (float4){0.f,0.f,0.f,0.f};
                vb[k] = (float4){0.f,0.f,0.f,0.f};
                if (idx >= 3328) continue;
                int f = idx % 26;
                int rr = (idx / 26) & 3;
                int cp = idx / 104;
                int gi = hb + 5 + rr;
                int gc0 = cbase - 4 + 4 * f;
                bool giok = (unsigned)gi < (unsigned)Hn;
                const float* r0 = xb + ((size_t)(2 * cp) * Hn + (giok ? gi : 0)) * Wn;
                const float* r1 = r0 + Hn * Wn;
                if (giok) {
                    if (gc0 >= 0 && gc0 <= Wn - 4) {
                        va[k] = *(const float4*)(r0 + gc0);
                        vb[k] = *(const float4*)(r1 + gc0);
                    } else {
                        float t0[4] = {0,0,0,0}, t1[4] = {0,0,0,0};
                        #pragma unroll
                        for (int j = 0; j < 4; ++j) {
                            int gc = gc0 + j;
                            if ((unsigned)gc < (unsigned)Wn) { t0[j] = r0[gc]; t1[j] = r1[gc]; }
                        }
                        va[k] = (float4){t0[0], t0[1], t0[2], t0[3]};
                        vb[k] = (float4){t1[0], t1[1], t1[2], t1[3]};
                    }
                }
            }
        }

        // ---- compute: wave row hb+r, 2m x 3n, barrier-free ----
        f32x4 acc[2][3];
        #pragma unroll
        for (int mi = 0; mi < 2; ++mi)
            #pragma unroll
            for (int i = 0; i < 3; ++i)
                acc[mi][i] = (f32x4){0.f, 0.f, 0.f, 0.f};

        #pragma unroll
        for (int sp = 0; sp < 9; ++sp) {
            const int dy = sp / 3, dx = sp % 3;
            int v = S + r + dy; if (v >= 6) v -= 6;    // slot of input row hb+r+dy-1
            int sb = v * SLOTB;
            int k3 = 3 * v;
            int c2base = ngg * 48 + pxw + dx;
            #pragma unroll
            for (int kh = 0; kh < 2; ++kh) {
                int ksl = kh * 4 + q;
                const unsigned char* mrow = (const unsigned char*)Mlds + sp * 8192 +
                                            rlane * 128 + ((ksl ^ (rlane & 7)) << 4);
                bf16x8 am0 = *(const bf16x8*)(mrow + (2 * mg) * 2048);
                bf16x8 am1 = *(const bf16x8*)(mrow + (2 * mg + 1) * 2048);
                bf16x8 bfr[3];
                #pragma unroll
                for (int i = 0; i < 3; ++i) {
                    int c2 = c2base + i * 16;
                    int key = (c2 + (c2 >> 3) + k3) & 7;
                    bfr[i] = *(const bf16x8*)(xsb + sb + c2 * 128 + ((ksl ^ key) << 4));
                }
                __builtin_amdgcn_s_setprio(1);
                #pragma unroll
                for (int i = 0; i < 3; ++i)
                    acc[0][i] = __builtin_amdgcn_mfma_f32_16x16x32_bf16(am0, bfr[i], acc[0][i], 0, 0, 0);
                #pragma unroll
                for (int i = 0; i < 3; ++i)
                    acc[1][i] = __builtin_amdgcn_mfma_f32_16x16x32_bf16(am1, bfr[i], acc[1][i], 0, 0, 0);
                __builtin_amdgcn_s_setprio(0);
            }
        }

        // ---- epilogue: +bias, real-only stores (row hb+r) ----
        {
            int h = hb + r;
            #pragma unroll
            for (int mi = 0; mi < 2; ++mi) {
                int rbase = (2 * mg + mi) * 16 + q * 4;
                float4 bq = *(const float4*)(g_b2 + rbase);
                float bvs[4] = {bq.x, bq.y, bq.z, bq.w};
                #pragma unroll
                for (int i = 0; i < 3; ++i) {
                    int px = cbase + ngg * 48 + i * 16 + pxw;
                    #pragma unroll
                    for (int jj = 0; jj < 4; ++jj)
                        out[(((size_t)(bb * Cn + rbase + jj)) * Hn + h) * Wn + px] =
                            acc[mi][i][jj] + bvs[jj];
                }
            }
        }

        __syncthreads();                  // all window reads for this step done

        // ---- xwrite: rows hb+5..hb+8 into retiring slots ----
        if (t < 2) {
            #pragma unroll
            for (int k = 0; k < 4; ++k) {
                int idx = tid + (k << 10);
                if (idx >= 3328) continue;
                int f = idx % 26;
                int rr = (idx / 26) & 3;
                int cp = idx / 104;
                int vslot = S + rr; if (vslot >= 6) vslot -= 6;   // (hb+6+rr)%6
                int chunk = cp >> 2, sub = (cp & 3) * 4;
                float v0[4] = {va[k].x, va[k].y, va[k].z, va[k].w};
                float v1[4] = {vb[k].x, vb[k].y, vb[k].z, vb[k].w};
                #pragma unroll
                for (int j = 0; j < 4; ++j) {
                    int c2 = 4 * f + j - 3;
                    if ((unsigned)c2 >= (unsigned)WCOLS) continue;
                    unsigned u;
                    asm("v_cvt_pk_bf16_f32 %0, %1, %2" : "=v"(u) : "v"(v0[j]), "v"(v1[j]));
                    int key = (c2 + (c2 >> 3) + 3 * vslot) & 7;
                    *(unsigned*)(xsb + vslot * SLOTB + c2 * 128 + ((chunk ^ key) << 4) + sub) = u;
                }
            }
        }
        __syncthreads();                  // publish new rows
    }
}

extern "C" void kernel_launch(void* const* d_in, const int* in_sizes, int n_in,
                              void* d_out, int out_size, void* d_ws, size_t ws_size,
                              hipStream_t stream) {
    const float* x    = (const float*)d_in[0];
    const float* cw   = (const float*)d_in[1];
    const float* A    = (const float*)d_in[2];
    const float* D    = (const float*)d_in[3];
    const float* bias = (const float*)d_in[4];
    const int*   perm = (const int*)d_in[5];

    acdc_precompute<<<dim3(64), dim3(256), 0, stream>>>(cw, A, D, bias, perm);
    acdc_main<<<dim3(NBLKS), dim3(1024), 0, stream>>>(x, (float*)d_out);
}